// Round 1
// baseline (283.255 us; speedup 1.0000x reference)
//
#include <hip/hip_runtime.h>
#include <cstdint>

typedef unsigned short u16;
typedef __bf16 bf16x8 __attribute__((ext_vector_type(8)));
typedef float f32x4 __attribute__((ext_vector_type(4)));

// ---- bf16 helpers (RTNE, matching XLA/ml_dtypes) ----
__device__ __forceinline__ u16 f2bf(float f) {
    unsigned u = __float_as_uint(f);
    u = (u + 0x7fffu + ((u >> 16) & 1u)) >> 16;
    return (u16)u;
}
__device__ __forceinline__ float bf2f(u16 h) {
    return __uint_as_float(((unsigned)h) << 16);
}

// ============================================================================
// 1. Ternary quantization. Replicates, in exact rounding order:
//    wb = bf16(w); scale = bf16(fp32_sum(|wb|)/64) (jax upcasts bf16 sums to f32)
//    t = bf16(wb/scale); q = clip(rint(t),-1,1); wq = q*scale (exact in bf16)
//    forward = bf16(wb + bf16(wq - wb))   <- STE sum computed in bf16!
// ============================================================================
__global__ __launch_bounds__(256) void quantize_ternary(
    const float* __restrict__ w, u16* __restrict__ out, int n_groups) {
    int g = blockIdx.x * 4 + (threadIdx.x >> 6);
    int lane = threadIdx.x & 63;
    if (g >= n_groups) return;
    float wf = w[(size_t)g * 64 + lane];
    u16 wb = f2bf(wf);
    float wbf = bf2f(wb);
    float a = fabsf(wbf);
    #pragma unroll
    for (int m = 1; m < 64; m <<= 1) a += __shfl_xor(a, m);
    float scale = bf2f(f2bf(a * (1.0f / 64.0f)));
    if (scale < 1e-8f) scale = 1e-8f;
    float t = bf2f(f2bf(wbf / scale));        // bf16 division semantics
    float q = rintf(t);                       // round half to even
    q = fminf(1.0f, fmaxf(-1.0f, q));
    float wq = q * scale;                     // exact (±scale or 0)
    float d = bf2f(f2bf(wq - wbf));           // bf16 subtract
    out[(size_t)g * 64 + lane] = f2bf(wbf + d); // bf16 add
}

// ============================================================================
// 2. fp32 -> bf16 cast, 8 elems/thread
// ============================================================================
__global__ __launch_bounds__(256) void cast_bf16(
    const float* __restrict__ x, u16* __restrict__ xb) {
    size_t i = ((size_t)blockIdx.x * 256 + threadIdx.x) * 8;
    float4 a = *(const float4*)(x + i);
    float4 b = *(const float4*)(x + i + 4);
    u16 o[8] = {f2bf(a.x), f2bf(a.y), f2bf(a.z), f2bf(a.w),
                f2bf(b.x), f2bf(b.y), f2bf(b.z), f2bf(b.w)};
    *(int4*)(xb + i) = *(const int4*)o;
}

// ============================================================================
// 3. GEMM: C[M,N] fp32 = A[M,K]bf16 @ B[N,K]bf16^T.  128x128 tile, BK=32,
//    4 waves each 64x64 (4x4 of 16x16x32 MFMA). LDS stride 40 bf16 -> 2-way
//    bank aliasing only (free).
// ============================================================================
__global__ __launch_bounds__(256) void gemm_bt(
    const u16* __restrict__ A, const u16* __restrict__ B,
    float* __restrict__ C, int M, int N, int K) {
    __shared__ u16 As[128][40];
    __shared__ u16 Bs[128][40];
    const int tid = threadIdx.x;
    const int lane = tid & 63, wid = tid >> 6;
    const int quad = lane >> 4, l16 = lane & 15;
    const int m0 = blockIdx.y * 128, n0 = blockIdx.x * 128;
    const int wm = (wid >> 1) * 64, wn = (wid & 1) * 64;
    const int srow = tid >> 2;          // 0..63
    const int scol = (tid & 3) * 8;     // 0,8,16,24
    f32x4 acc[4][4];
    f32x4 zero = {0.f, 0.f, 0.f, 0.f};
    #pragma unroll
    for (int i = 0; i < 4; ++i)
        #pragma unroll
        for (int j = 0; j < 4; ++j) acc[i][j] = zero;
    for (int k0 = 0; k0 < K; k0 += 32) {
        __syncthreads();
        *(int4*)(&As[srow][scol])      = *(const int4*)(A + (size_t)(m0 + srow) * K + k0 + scol);
        *(int4*)(&As[srow + 64][scol]) = *(const int4*)(A + (size_t)(m0 + srow + 64) * K + k0 + scol);
        *(int4*)(&Bs[srow][scol])      = *(const int4*)(B + (size_t)(n0 + srow) * K + k0 + scol);
        *(int4*)(&Bs[srow + 64][scol]) = *(const int4*)(B + (size_t)(n0 + srow + 64) * K + k0 + scol);
        __syncthreads();
        bf16x8 af[4], bfr[4];
        #pragma unroll
        for (int mi = 0; mi < 4; ++mi) af[mi]  = *(const bf16x8*)(&As[wm + mi * 16 + l16][quad * 8]);
        #pragma unroll
        for (int ni = 0; ni < 4; ++ni) bfr[ni] = *(const bf16x8*)(&Bs[wn + ni * 16 + l16][quad * 8]);
        #pragma unroll
        for (int mi = 0; mi < 4; ++mi)
            #pragma unroll
            for (int ni = 0; ni < 4; ++ni)
                acc[mi][ni] = __builtin_amdgcn_mfma_f32_16x16x32_bf16(af[mi], bfr[ni], acc[mi][ni], 0, 0, 0);
    }
    // C/D layout: col = lane&15, row = quad*4 + reg
    #pragma unroll
    for (int mi = 0; mi < 4; ++mi)
        #pragma unroll
        for (int ni = 0; ni < 4; ++ni) {
            int rg = m0 + wm + mi * 16 + quad * 4;
            int cg = n0 + wn + ni * 16 + l16;
            float* cp = C + (size_t)rg * N + cg;
            #pragma unroll
            for (int r = 0; r < 4; ++r) cp[(size_t)r * N] = acc[mi][ni][r];
        }
}

// ============================================================================
// 4. Fusion: per-token head-RMSNorm + RoPE + gain; writes
//    Qb[b][h][s][d], Kb[b][kv][s][d] bf16, and V transposed Vt[b][kv][d][s].
//    Block = 16 tokens; lane layout: lh=lane>>4 picks head-of-4, l16=lane&15
//    covers d in 4-float chunks. RoPE partner via shfl_xor(8).
// ============================================================================
__global__ __launch_bounds__(256) void fuse_qkv(
    const float* __restrict__ qkv, const float* __restrict__ gain,
    u16* __restrict__ Qb, u16* __restrict__ Kb, u16* __restrict__ Vt) {
    __shared__ u16 Vs[16][264];
    const int tid = threadIdx.x;
    const int lane = tid & 63, wid = tid >> 6;
    const int lh = lane >> 4, l16 = lane & 15;
    const int T0 = blockIdx.x * 16;
    const int dbase = l16 * 4;
    const bool hi = dbase >= 32;
    const int ibase = hi ? dbase - 32 : dbase;
    const float sgn = hi ? -1.0f : 1.0f;
    const float eps = 1.1920929e-7f;

    float invf[4];
    #pragma unroll
    for (int j = 0; j < 4; ++j)
        invf[j] = (float)(1.0 / pow(10000.0, (double)(ibase + j) / 32.0));

    for (int i = 0; i < 4; ++i) {
        int tok = T0 + wid * 4 + i;
        int b = tok >> 11, s = tok & 2047;
        float cosv[4], sinv[4];
        #pragma unroll
        for (int j = 0; j < 4; ++j) {
            float fr = (float)s * invf[j];
            cosv[j] = cosf(fr);
            sinv[j] = sinf(fr);
        }
        const float* row = qkv + (size_t)tok * 1536;
        // ---- Q: 4 passes x 4 heads ----
        #pragma unroll
        for (int p = 0; p < 4; ++p) {
            int h = p * 4 + lh;
            float4 x = *(const float4*)(row + h * 64 + dbase);
            float ss = x.x * x.x + x.y * x.y + x.z * x.z + x.w * x.w;
            #pragma unroll
            for (int m = 1; m < 16; m <<= 1) ss += __shfl_xor(ss, m);
            float rn = 1.0f / sqrtf(ss * (1.0f / 64.0f) + eps);
            float xn0 = x.x * rn, xn1 = x.y * rn, xn2 = x.z * rn, xn3 = x.w * rn;
            float p0 = __shfl_xor(xn0, 8), p1 = __shfl_xor(xn1, 8);
            float p2 = __shfl_xor(xn2, 8), p3 = __shfl_xor(xn3, 8);
            float g = gain[h];
            u16 o[4] = {f2bf((xn0 * cosv[0] + sgn * p0 * sinv[0]) * g),
                        f2bf((xn1 * cosv[1] + sgn * p1 * sinv[1]) * g),
                        f2bf((xn2 * cosv[2] + sgn * p2 * sinv[2]) * g),
                        f2bf((xn3 * cosv[3] + sgn * p3 * sinv[3]) * g)};
            *(uint2*)(Qb + (((size_t)(b * 16 + h) * 2048 + s) * 64 + dbase)) = *(const uint2*)o;
        }
        // ---- K: 1 pass (head = lh) ----
        {
            float4 x = *(const float4*)(row + 1024 + lh * 64 + dbase);
            float ss = x.x * x.x + x.y * x.y + x.z * x.z + x.w * x.w;
            #pragma unroll
            for (int m = 1; m < 16; m <<= 1) ss += __shfl_xor(ss, m);
            float rn = 1.0f / sqrtf(ss * (1.0f / 64.0f) + eps);
            float xn0 = x.x * rn, xn1 = x.y * rn, xn2 = x.z * rn, xn3 = x.w * rn;
            float p0 = __shfl_xor(xn0, 8), p1 = __shfl_xor(xn1, 8);
            float p2 = __shfl_xor(xn2, 8), p3 = __shfl_xor(xn3, 8);
            u16 o[4] = {f2bf(xn0 * cosv[0] + sgn * p0 * sinv[0]),
                        f2bf(xn1 * cosv[1] + sgn * p1 * sinv[1]),
                        f2bf(xn2 * cosv[2] + sgn * p2 * sinv[2]),
                        f2bf(xn3 * cosv[3] + sgn * p3 * sinv[3])};
            *(uint2*)(Kb + (((size_t)(b * 4 + lh) * 2048 + s) * 64 + dbase)) = *(const uint2*)o;
        }
        // ---- V: bf16 into LDS for transpose ----
        {
            float4 x = *(const float4*)(row + 1280 + lh * 64 + dbase);
            u16 o[4] = {f2bf(x.x), f2bf(x.y), f2bf(x.z), f2bf(x.w)};
            int sl = wid * 4 + i;
            *(uint2*)(&Vs[sl][lh * 64 + dbase]) = *(const uint2*)o;
        }
    }
    __syncthreads();
    // ---- V transpose out: thread owns one (kv,d) row ----
    {
        int kvh = tid >> 6, d = tid & 63;
        int b0 = T0 >> 11, s0 = T0 & 2047;
        u16 tmp[16];
        #pragma unroll
        for (int sl = 0; sl < 16; ++sl) tmp[sl] = Vs[sl][kvh * 64 + d];
        u16* dst = Vt + ((size_t)(b0 * 4 + kvh) * 64 + d) * 2048 + s0;
        *(int4*)(dst) = *(const int4*)(tmp);
        *(int4*)(dst + 8) = *(const int4*)(tmp + 8);
    }
}

// ============================================================================
// 5. Flash attention. Block = (qtile 64 rows, head, batch); 4 waves x 16 rows.
//    K-tiles of 64. S via mfma(Q,K); online softmax fp32; P through LDS into
//    A-layout; O += mfma(P, Vt). LDS stride 72 -> 2-way banks.
// ============================================================================
__global__ __launch_bounds__(256) void attn(
    const u16* __restrict__ Qb, const u16* __restrict__ Kb,
    const u16* __restrict__ Vt, float* __restrict__ y) {
    __shared__ u16 Qs[64][72], Ks[64][72], Vsh[64][72], Ps[64][72];
    const int qt = blockIdx.x, h = blockIdx.y, b = blockIdx.z;
    const int kvh = h >> 2;
    const int q0 = qt * 64;
    const int tid = threadIdx.x, lane = tid & 63, w = tid >> 6;
    const int quad = lane >> 4, l16 = lane & 15;

    const u16* Qg = Qb + ((size_t)(b * 16 + h) * 2048 + q0) * 64;
    const u16* Kg = Kb + (size_t)(b * 4 + kvh) * 2048 * 64;
    const u16* Vg = Vt + (size_t)(b * 4 + kvh) * 64 * 2048;

    #pragma unroll
    for (int c = 0; c < 2; ++c) {
        int idx = tid + 256 * c, r = idx >> 3, col = (idx & 7) * 8;
        *(int4*)(&Qs[r][col]) = *(const int4*)(Qg + (size_t)r * 64 + col);
    }
    __syncthreads();
    bf16x8 qa0 = *(const bf16x8*)(&Qs[w * 16 + l16][quad * 8]);
    bf16x8 qa1 = *(const bf16x8*)(&Qs[w * 16 + l16][32 + quad * 8]);

    f32x4 oacc[4];
    f32x4 zero = {0.f, 0.f, 0.f, 0.f};
    #pragma unroll
    for (int t = 0; t < 4; ++t) oacc[t] = zero;
    float mrow[4], lrow[4];
    #pragma unroll
    for (int r = 0; r < 4; ++r) { mrow[r] = -INFINITY; lrow[r] = 0.f; }

    for (int j0 = 0; j0 <= q0; j0 += 64) {
        #pragma unroll
        for (int c = 0; c < 2; ++c) {
            int idx = tid + 256 * c, r = idx >> 3, col = (idx & 7) * 8;
            *(int4*)(&Ks[r][col])  = *(const int4*)(Kg + (size_t)(j0 + r) * 64 + col);
            *(int4*)(&Vsh[r][col]) = *(const int4*)(Vg + (size_t)r * 2048 + j0 + col);
        }
        __syncthreads();
        // S = Q K^T * 0.125, masked on the diagonal tile
        f32x4 st[4];
        #pragma unroll
        for (int t = 0; t < 4; ++t) {
            f32x4 s = zero;
            bf16x8 kb0 = *(const bf16x8*)(&Ks[t * 16 + l16][quad * 8]);
            bf16x8 kb1 = *(const bf16x8*)(&Ks[t * 16 + l16][32 + quad * 8]);
            s = __builtin_amdgcn_mfma_f32_16x16x32_bf16(qa0, kb0, s, 0, 0, 0);
            s = __builtin_amdgcn_mfma_f32_16x16x32_bf16(qa1, kb1, s, 0, 0, 0);
            st[t] = s;
        }
        const bool diag = (j0 == q0);
        #pragma unroll
        for (int t = 0; t < 4; ++t)
            #pragma unroll
            for (int r = 0; r < 4; ++r) {
                float v = st[t][r] * 0.125f;
                if (diag && (j0 + t * 16 + l16 > q0 + w * 16 + quad * 4 + r)) v = -INFINITY;
                st[t][r] = v;
            }
        // online softmax
        float mnew[4], alpha[4];
        #pragma unroll
        for (int r = 0; r < 4; ++r) {
            float mx = fmaxf(fmaxf(st[0][r], st[1][r]), fmaxf(st[2][r], st[3][r]));
            #pragma unroll
            for (int m = 1; m < 16; m <<= 1) mx = fmaxf(mx, __shfl_xor(mx, m));
            mnew[r] = fmaxf(mrow[r], mx);
            alpha[r] = __expf(mrow[r] - mnew[r]);
            mrow[r] = mnew[r];
        }
        float rowsum[4] = {0.f, 0.f, 0.f, 0.f};
        #pragma unroll
        for (int t = 0; t < 4; ++t)
            #pragma unroll
            for (int r = 0; r < 4; ++r) {
                float p = __expf(st[t][r] - mnew[r]);
                st[t][r] = p;
                rowsum[r] += p;
            }
        #pragma unroll
        for (int r = 0; r < 4; ++r) {
            float rs = rowsum[r];
            #pragma unroll
            for (int m = 1; m < 16; m <<= 1) rs += __shfl_xor(rs, m);
            lrow[r] = lrow[r] * alpha[r] + rs;
            #pragma unroll
            for (int t = 0; t < 4; ++t) oacc[t][r] *= alpha[r];
        }
        // P -> LDS (C layout) -> A layout frags
        #pragma unroll
        for (int t = 0; t < 4; ++t)
            #pragma unroll
            for (int r = 0; r < 4; ++r)
                Ps[w * 16 + quad * 4 + r][t * 16 + l16] = f2bf(st[t][r]);
        __syncthreads();
        bf16x8 pa0 = *(const bf16x8*)(&Ps[w * 16 + l16][quad * 8]);
        bf16x8 pa1 = *(const bf16x8*)(&Ps[w * 16 + l16][32 + quad * 8]);
        #pragma unroll
        for (int t = 0; t < 4; ++t) {
            bf16x8 vb0 = *(const bf16x8*)(&Vsh[t * 16 + l16][quad * 8]);
            bf16x8 vb1 = *(const bf16x8*)(&Vsh[t * 16 + l16][32 + quad * 8]);
            oacc[t] = __builtin_amdgcn_mfma_f32_16x16x32_bf16(pa0, vb0, oacc[t], 0, 0, 0);
            oacc[t] = __builtin_amdgcn_mfma_f32_16x16x32_bf16(pa1, vb1, oacc[t], 0, 0, 0);
        }
        __syncthreads();
    }
    // epilogue: y[b*2048+row][h*64+col]
    #pragma unroll
    for (int t = 0; t < 4; ++t)
        #pragma unroll
        for (int r = 0; r < 4; ++r) {
            int rg = q0 + w * 16 + quad * 4 + r;
            int cg = h * 64 + t * 16 + l16;
            y[((size_t)b * 2048 + rg) * 1024 + cg] = oacc[t][r] / lrow[r];
        }
}

// ============================================================================
// 6. Row RMSNorm (dim 1024) -> bf16
// ============================================================================
__global__ __launch_bounds__(256) void rmsnorm_rows(
    const float* __restrict__ y, u16* __restrict__ yb) {
    __shared__ float red[4];
    const int row = blockIdx.x, tid = threadIdx.x;
    const float* p = y + (size_t)row * 1024 + tid * 4;
    float4 v = *(const float4*)p;
    float ss = v.x * v.x + v.y * v.y + v.z * v.z + v.w * v.w;
    #pragma unroll
    for (int m = 1; m < 64; m <<= 1) ss += __shfl_xor(ss, m);
    if ((tid & 63) == 0) red[tid >> 6] = ss;
    __syncthreads();
    float tot = red[0] + red[1] + red[2] + red[3];
    float rn = 1.0f / sqrtf(tot * (1.0f / 1024.0f) + 1.1920929e-7f);
    u16 o[4] = {f2bf(v.x * rn), f2bf(v.y * rn), f2bf(v.z * rn), f2bf(v.w * rn)};
    *(uint2*)(yb + (size_t)row * 1024 + tid * 4) = *(const uint2*)o;
}

// ============================================================================
// launch
// ============================================================================
extern "C" void kernel_launch(void* const* d_in, const int* in_sizes, int n_in,
                              void* d_out, int out_size, void* d_ws, size_t ws_size,
                              hipStream_t stream) {
    const float* x      = (const float*)d_in[0];
    const float* w_qkv  = (const float*)d_in[1];
    const float* w_proj = (const float*)d_in[2];
    const float* q_gain = (const float*)d_in[3];
    float* out = (float*)d_out;
    char* ws = (char*)d_ws;

    u16*   wqkv_b  = (u16*)(ws);                    // 1536*1024*2 = 3,145,728
    u16*   wproj_b = (u16*)(ws + 3145728);          // 1024*1024*2 = 2,097,152
    u16*   xb      = (u16*)(ws + 5242880);          // 8,388,608 (aliased: yb later)
    float* qkv     = (float*)(ws + 13631488);       // 25,165,824 (aliased: y later)
    u16*   Qb      = (u16*)(ws + 38797312);         // 8,388,608
    u16*   Kb      = (u16*)(ws + 47185920);         // 2,097,152
    u16*   Vt      = (u16*)(ws + 49283072);         // 2,097,152  -> total 51.4 MB
    float* y  = qkv;   // qkv dead after fuse_qkv
    u16*   yb = xb;    // xb dead after GEMM1

    quantize_ternary<<<6144, 256, 0, stream>>>(w_qkv, wqkv_b, 24576);
    quantize_ternary<<<4096, 256, 0, stream>>>(w_proj, wproj_b, 16384);
    cast_bf16<<<2048, 256, 0, stream>>>(x, xb);
    gemm_bt<<<dim3(12, 32), 256, 0, stream>>>(xb, wqkv_b, qkv, 4096, 1536, 1024);
    fuse_qkv<<<256, 256, 0, stream>>>(qkv, q_gain, Qb, Kb, Vt);
    attn<<<dim3(32, 16, 2), 256, 0, stream>>>(Qb, Kb, Vt, y);
    rmsnorm_rows<<<4096, 256, 0, stream>>>(y, yb);
    gemm_bt<<<dim3(8, 32), 256, 0, stream>>>(yb, wproj_b, out, 4096, 1024, 1024);
}

// Round 2
// 270.531 us; speedup vs baseline: 1.0470x; 1.0470x over previous
//
#include <hip/hip_runtime.h>
#include <cstdint>

typedef unsigned short u16;
typedef __bf16 bf16x8 __attribute__((ext_vector_type(8)));
typedef short s16x4 __attribute__((ext_vector_type(4)));
typedef float f32x4 __attribute__((ext_vector_type(4)));

// ---- bf16 helpers (RTNE, matching XLA/ml_dtypes) ----
__device__ __forceinline__ u16 f2bf(float f) {
    unsigned u = __float_as_uint(f);
    u = (u + 0x7fffu + ((u >> 16) & 1u)) >> 16;
    return (u16)u;
}
__device__ __forceinline__ float bf2f(u16 h) {
    return __uint_as_float(((unsigned)h) << 16);
}

// 16x16x16 bf16 MFMA (K=16): B-operand layout B[n=l16][k=quad*4+j] matches the
// C-layout of a preceding S^T mfma exactly -> P never touches LDS.
#if __has_builtin(__builtin_amdgcn_mfma_f32_16x16x16bf16_1k)
#define MFMA16(a, b, c) __builtin_amdgcn_mfma_f32_16x16x16bf16_1k(a, b, c, 0, 0, 0)
#else
static __device__ __forceinline__ f32x4 mfma16_asm(s16x4 a, s16x4 b, f32x4 c) {
    asm("v_mfma_f32_16x16x16_bf16 %0, %1, %2, %0" : "+v"(c) : "v"(a), "v"(b));
    return c;
}
#define MFMA16(a, b, c) mfma16_asm(a, b, c)
#endif

// ============================================================================
// 1. Ternary quantization (bit-exact rounding order vs JAX reference)
// ============================================================================
__global__ __launch_bounds__(256) void quantize_ternary(
    const float* __restrict__ w, u16* __restrict__ out, int n_groups) {
    int g = blockIdx.x * 4 + (threadIdx.x >> 6);
    int lane = threadIdx.x & 63;
    if (g >= n_groups) return;
    float wf = w[(size_t)g * 64 + lane];
    u16 wb = f2bf(wf);
    float wbf = bf2f(wb);
    float a = fabsf(wbf);
    #pragma unroll
    for (int m = 1; m < 64; m <<= 1) a += __shfl_xor(a, m);
    float scale = bf2f(f2bf(a * (1.0f / 64.0f)));
    if (scale < 1e-8f) scale = 1e-8f;
    float t = bf2f(f2bf(wbf / scale));
    float q = rintf(t);
    q = fminf(1.0f, fmaxf(-1.0f, q));
    float wq = q * scale;
    float d = bf2f(f2bf(wq - wbf));
    out[(size_t)g * 64 + lane] = f2bf(wbf + d);
}

// ============================================================================
// 2. fp32 -> bf16 cast
// ============================================================================
__global__ __launch_bounds__(256) void cast_bf16(
    const float* __restrict__ x, u16* __restrict__ xb) {
    size_t i = ((size_t)blockIdx.x * 256 + threadIdx.x) * 8;
    float4 a = *(const float4*)(x + i);
    float4 b = *(const float4*)(x + i + 4);
    u16 o[8] = {f2bf(a.x), f2bf(a.y), f2bf(a.z), f2bf(a.w),
                f2bf(b.x), f2bf(b.y), f2bf(b.z), f2bf(b.w)};
    *(int4*)(xb + i) = *(const int4*)o;
}

// ============================================================================
// 3. GEMM: C[M,N] fp32 = A[M,K]bf16 @ B[N,K]bf16^T  (unchanged this round)
// ============================================================================
__global__ __launch_bounds__(256) void gemm_bt(
    const u16* __restrict__ A, const u16* __restrict__ B,
    float* __restrict__ C, int M, int N, int K) {
    __shared__ u16 As[128][40];
    __shared__ u16 Bs[128][40];
    const int tid = threadIdx.x;
    const int lane = tid & 63, wid = tid >> 6;
    const int quad = lane >> 4, l16 = lane & 15;
    const int m0 = blockIdx.y * 128, n0 = blockIdx.x * 128;
    const int wm = (wid >> 1) * 64, wn = (wid & 1) * 64;
    const int srow = tid >> 2;
    const int scol = (tid & 3) * 8;
    f32x4 acc[4][4];
    f32x4 zero = {0.f, 0.f, 0.f, 0.f};
    #pragma unroll
    for (int i = 0; i < 4; ++i)
        #pragma unroll
        for (int j = 0; j < 4; ++j) acc[i][j] = zero;
    for (int k0 = 0; k0 < K; k0 += 32) {
        __syncthreads();
        *(int4*)(&As[srow][scol])      = *(const int4*)(A + (size_t)(m0 + srow) * K + k0 + scol);
        *(int4*)(&As[srow + 64][scol]) = *(const int4*)(A + (size_t)(m0 + srow + 64) * K + k0 + scol);
        *(int4*)(&Bs[srow][scol])      = *(const int4*)(B + (size_t)(n0 + srow) * K + k0 + scol);
        *(int4*)(&Bs[srow + 64][scol]) = *(const int4*)(B + (size_t)(n0 + srow + 64) * K + k0 + scol);
        __syncthreads();
        bf16x8 af[4], bfr[4];
        #pragma unroll
        for (int mi = 0; mi < 4; ++mi) af[mi]  = *(const bf16x8*)(&As[wm + mi * 16 + l16][quad * 8]);
        #pragma unroll
        for (int ni = 0; ni < 4; ++ni) bfr[ni] = *(const bf16x8*)(&Bs[wn + ni * 16 + l16][quad * 8]);
        #pragma unroll
        for (int mi = 0; mi < 4; ++mi)
            #pragma unroll
            for (int ni = 0; ni < 4; ++ni)
                acc[mi][ni] = __builtin_amdgcn_mfma_f32_16x16x32_bf16(af[mi], bfr[ni], acc[mi][ni], 0, 0, 0);
    }
    #pragma unroll
    for (int mi = 0; mi < 4; ++mi)
        #pragma unroll
        for (int ni = 0; ni < 4; ++ni) {
            int rg = m0 + wm + mi * 16 + quad * 4;
            int cg = n0 + wn + ni * 16 + l16;
            float* cp = C + (size_t)rg * N + cg;
            #pragma unroll
            for (int r = 0; r < 4; ++r) cp[(size_t)r * N] = acc[mi][ni][r];
        }
}

// ============================================================================
// 4. Fusion: head-RMSNorm + RoPE + gain; Qb[b][h][s][d], Kb[b][kv][s][d],
//    V transposed Vt[b][kv][d][s].  (unchanged)
// ============================================================================
__global__ __launch_bounds__(256) void fuse_qkv(
    const float* __restrict__ qkv, const float* __restrict__ gain,
    u16* __restrict__ Qb, u16* __restrict__ Kb, u16* __restrict__ Vt) {
    __shared__ u16 Vs[16][264];
    const int tid = threadIdx.x;
    const int lane = tid & 63, wid = tid >> 6;
    const int lh = lane >> 4, l16 = lane & 15;
    const int T0 = blockIdx.x * 16;
    const int dbase = l16 * 4;
    const bool hi = dbase >= 32;
    const int ibase = hi ? dbase - 32 : dbase;
    const float sgn = hi ? -1.0f : 1.0f;
    const float eps = 1.1920929e-7f;

    float invf[4];
    #pragma unroll
    for (int j = 0; j < 4; ++j)
        invf[j] = (float)(1.0 / pow(10000.0, (double)(ibase + j) / 32.0));

    for (int i = 0; i < 4; ++i) {
        int tok = T0 + wid * 4 + i;
        int b = tok >> 11, s = tok & 2047;
        float cosv[4], sinv[4];
        #pragma unroll
        for (int j = 0; j < 4; ++j) {
            float fr = (float)s * invf[j];
            cosv[j] = cosf(fr);
            sinv[j] = sinf(fr);
        }
        const float* row = qkv + (size_t)tok * 1536;
        #pragma unroll
        for (int p = 0; p < 4; ++p) {
            int h = p * 4 + lh;
            float4 x = *(const float4*)(row + h * 64 + dbase);
            float ss = x.x * x.x + x.y * x.y + x.z * x.z + x.w * x.w;
            #pragma unroll
            for (int m = 1; m < 16; m <<= 1) ss += __shfl_xor(ss, m);
            float rn = 1.0f / sqrtf(ss * (1.0f / 64.0f) + eps);
            float xn0 = x.x * rn, xn1 = x.y * rn, xn2 = x.z * rn, xn3 = x.w * rn;
            float p0 = __shfl_xor(xn0, 8), p1 = __shfl_xor(xn1, 8);
            float p2 = __shfl_xor(xn2, 8), p3 = __shfl_xor(xn3, 8);
            float g = gain[h];
            u16 o[4] = {f2bf((xn0 * cosv[0] + sgn * p0 * sinv[0]) * g),
                        f2bf((xn1 * cosv[1] + sgn * p1 * sinv[1]) * g),
                        f2bf((xn2 * cosv[2] + sgn * p2 * sinv[2]) * g),
                        f2bf((xn3 * cosv[3] + sgn * p3 * sinv[3]) * g)};
            *(uint2*)(Qb + (((size_t)(b * 16 + h) * 2048 + s) * 64 + dbase)) = *(const uint2*)o;
        }
        {
            float4 x = *(const float4*)(row + 1024 + lh * 64 + dbase);
            float ss = x.x * x.x + x.y * x.y + x.z * x.z + x.w * x.w;
            #pragma unroll
            for (int m = 1; m < 16; m <<= 1) ss += __shfl_xor(ss, m);
            float rn = 1.0f / sqrtf(ss * (1.0f / 64.0f) + eps);
            float xn0 = x.x * rn, xn1 = x.y * rn, xn2 = x.z * rn, xn3 = x.w * rn;
            float p0 = __shfl_xor(xn0, 8), p1 = __shfl_xor(xn1, 8);
            float p2 = __shfl_xor(xn2, 8), p3 = __shfl_xor(xn3, 8);
            u16 o[4] = {f2bf(xn0 * cosv[0] + sgn * p0 * sinv[0]),
                        f2bf(xn1 * cosv[1] + sgn * p1 * sinv[1]),
                        f2bf(xn2 * cosv[2] + sgn * p2 * sinv[2]),
                        f2bf(xn3 * cosv[3] + sgn * p3 * sinv[3])};
            *(uint2*)(Kb + (((size_t)(b * 4 + lh) * 2048 + s) * 64 + dbase)) = *(const uint2*)o;
        }
        {
            float4 x = *(const float4*)(row + 1280 + lh * 64 + dbase);
            u16 o[4] = {f2bf(x.x), f2bf(x.y), f2bf(x.z), f2bf(x.w)};
            int sl = wid * 4 + i;
            *(uint2*)(&Vs[sl][lh * 64 + dbase]) = *(const uint2*)o;
        }
    }
    __syncthreads();
    {
        int kvh = tid >> 6, d = tid & 63;
        int b0 = T0 >> 11, s0 = T0 & 2047;
        u16 tmp[16];
        #pragma unroll
        for (int sl = 0; sl < 16; ++sl) tmp[sl] = Vs[sl][kvh * 64 + d];
        u16* dst = Vt + ((size_t)(b0 * 4 + kvh) * 64 + d) * 2048 + s0;
        *(int4*)(dst) = *(const int4*)(tmp);
        *(int4*)(dst + 8) = *(const int4*)(tmp + 8);
    }
}

// ============================================================================
// 5. Flash attention, TRANSPOSED: S^T = mfma(K,Q) so each lane owns ONE q-row
//    (q = l16): softmax state is lane-scalar, row reduce = 2 shuffles, and
//    P^T (C-layout [k=quad*4+r][q=l16]) feeds 16x16x16 PV mfma directly from
//    registers (B-operand layout matches) -> no P LDS round-trip, 2 barriers.
//    K/V register-prefetch overlaps global loads with compute.
//    Grid: x = h+16*b (32), y: qt = 31-y  (heavy blocks dispatch first, LPT).
// ============================================================================
__global__ __launch_bounds__(256) void attn(
    const u16* __restrict__ Qb, const u16* __restrict__ Kb,
    const u16* __restrict__ Vt, float* __restrict__ y) {
    __shared__ u16 Qs[64][72], Ks[64][72], Vsh[64][72];
    const int hb = blockIdx.x;
    const int h = hb & 15, b = hb >> 4;
    const int qt = 31 - blockIdx.y;
    const int q0 = qt * 64;
    const int kvh = h >> 2;
    const int tid = threadIdx.x, lane = tid & 63, w = tid >> 6;
    const int quad = lane >> 4, l16 = lane & 15;

    const u16* Qg = Qb + ((size_t)(b * 16 + h) * 2048 + q0) * 64;
    const u16* Kg = Kb + (size_t)(b * 4 + kvh) * 2048 * 64;
    const u16* Vg = Vt + (size_t)(b * 4 + kvh) * 64 * 2048;

    // stage Q (64x64 bf16)
    #pragma unroll
    for (int c = 0; c < 2; ++c) {
        int idx = tid + 256 * c, r = idx >> 3, col = (idx & 7) * 8;
        *(int4*)(&Qs[r][col]) = *(const int4*)(Qg + (size_t)r * 64 + col);
    }
    // prefetch K/V tile 0 into registers
    const int pr = tid >> 3, pc = (tid & 7) * 8;   // pr 0..31, pc 0..56
    int4 kreg[2], vreg[2];
    kreg[0] = *(const int4*)(Kg + (size_t)pr * 64 + pc);
    kreg[1] = *(const int4*)(Kg + (size_t)(pr + 32) * 64 + pc);
    vreg[0] = *(const int4*)(Vg + (size_t)pr * 2048 + pc);
    vreg[1] = *(const int4*)(Vg + (size_t)(pr + 32) * 2048 + pc);

    __syncthreads();
    const bf16x8 qa0 = *(const bf16x8*)(&Qs[w * 16 + l16][quad * 8]);
    const bf16x8 qa1 = *(const bf16x8*)(&Qs[w * 16 + l16][32 + quad * 8]);

    f32x4 oacc[4];
    f32x4 zero = {0.f, 0.f, 0.f, 0.f};
    #pragma unroll
    for (int t = 0; t < 4; ++t) oacc[t] = zero;
    float m = -INFINITY, l = 0.f;
    const float sc = 0.18033688011112042f;  // 0.125 * log2(e): softmax in base-2

    for (int j0 = 0; j0 <= q0; j0 += 64) {
        __syncthreads();   // previous tile's compute done
        *(int4*)(&Ks[pr][pc])       = kreg[0];
        *(int4*)(&Ks[pr + 32][pc])  = kreg[1];
        *(int4*)(&Vsh[pr][pc])      = vreg[0];
        *(int4*)(&Vsh[pr + 32][pc]) = vreg[1];
        if (j0 + 64 <= q0) {       // prefetch next tile; flies during compute
            kreg[0] = *(const int4*)(Kg + (size_t)(j0 + 64 + pr) * 64 + pc);
            kreg[1] = *(const int4*)(Kg + (size_t)(j0 + 96 + pr) * 64 + pc);
            vreg[0] = *(const int4*)(Vg + (size_t)pr * 2048 + j0 + 64 + pc);
            vreg[1] = *(const int4*)(Vg + (size_t)(pr + 32) * 2048 + j0 + 64 + pc);
        }
        __syncthreads();   // LDS visible

        const bool diag = (j0 == q0);
        const int tmax = diag ? (w + 1) : 4;   // wave-uniform

        // S^T: D[k=quad*4+r][q=l16] per 16-tile t
        f32x4 st[4];
        #pragma unroll
        for (int t = 0; t < 4; ++t) {
            if (t < tmax) {
                bf16x8 kb0 = *(const bf16x8*)(&Ks[t * 16 + l16][quad * 8]);
                bf16x8 kb1 = *(const bf16x8*)(&Ks[t * 16 + l16][32 + quad * 8]);
                f32x4 s = zero;
                s = __builtin_amdgcn_mfma_f32_16x16x32_bf16(kb0, qa0, s, 0, 0, 0);
                s = __builtin_amdgcn_mfma_f32_16x16x32_bf16(kb1, qa1, s, 0, 0, 0);
                st[t] = s;
            }
        }
        // scale to log2 domain + causal mask (only t==w on diag tile is partial)
        float mx = -1e30f;
        #pragma unroll
        for (int t = 0; t < 4; ++t) {
            if (t < tmax) {
                #pragma unroll
                for (int r = 0; r < 4; ++r) {
                    float v = st[t][r] * sc;
                    if (diag && t == w && (quad * 4 + r > l16)) v = -1e30f;
                    st[t][r] = v;
                    mx = fmaxf(mx, v);
                }
            }
        }
        mx = fmaxf(mx, __shfl_xor(mx, 16));
        mx = fmaxf(mx, __shfl_xor(mx, 32));
        float mnew = fmaxf(m, mx);
        float alpha = __builtin_amdgcn_exp2f(m - mnew);
        m = mnew;
        float rs = 0.f;
        s16x4 pf[4];
        #pragma unroll
        for (int t = 0; t < 4; ++t) {
            if (t < tmax) {
                #pragma unroll
                for (int r = 0; r < 4; ++r) {
                    float p = __builtin_amdgcn_exp2f(st[t][r] - mnew);
                    rs += p;
                    pf[t][r] = (short)f2bf(p);
                }
            }
        }
        rs += __shfl_xor(rs, 16);
        rs += __shfl_xor(rs, 32);
        l = l * alpha + rs;
        #pragma unroll
        for (int t = 0; t < 4; ++t) oacc[t] *= alpha;

        // PV: O^T[d=quad*4+r][q=l16] += V^T-frag x P^T-frag, K=16 mfma
        #pragma unroll
        for (int dt = 0; dt < 4; ++dt)
            #pragma unroll
            for (int kt = 0; kt < 4; ++kt)
                if (kt < tmax) {
                    s16x4 va = *(const s16x4*)(&Vsh[dt * 16 + l16][kt * 16 + quad * 4]);
                    oacc[dt] = MFMA16(va, pf[kt], oacc[dt]);
                }
    }
    // epilogue: lane's q-row = q0 + w*16 + l16; d = dt*16 + quad*4 + r
    const float inv = 1.0f / l;
    const size_t row = (size_t)b * 2048 + q0 + w * 16 + l16;
    #pragma unroll
    for (int dt = 0; dt < 4; ++dt) {
        f32x4 o = oacc[dt] * inv;
        *(f32x4*)(&y[row * 1024 + h * 64 + dt * 16 + quad * 4]) = o;
    }
}

// ============================================================================
// 6. Row RMSNorm (dim 1024) -> bf16
// ============================================================================
__global__ __launch_bounds__(256) void rmsnorm_rows(
    const float* __restrict__ y, u16* __restrict__ yb) {
    __shared__ float red[4];
    const int row = blockIdx.x, tid = threadIdx.x;
    const float* p = y + (size_t)row * 1024 + tid * 4;
    float4 v = *(const float4*)p;
    float ss = v.x * v.x + v.y * v.y + v.z * v.z + v.w * v.w;
    #pragma unroll
    for (int m = 1; m < 64; m <<= 1) ss += __shfl_xor(ss, m);
    if ((tid & 63) == 0) red[tid >> 6] = ss;
    __syncthreads();
    float tot = red[0] + red[1] + red[2] + red[3];
    float rn = 1.0f / sqrtf(tot * (1.0f / 1024.0f) + 1.1920929e-7f);
    u16 o[4] = {f2bf(v.x * rn), f2bf(v.y * rn), f2bf(v.z * rn), f2bf(v.w * rn)};
    *(uint2*)(yb + (size_t)row * 1024 + tid * 4) = *(const uint2*)o;
}

// ============================================================================
// launch
// ============================================================================
extern "C" void kernel_launch(void* const* d_in, const int* in_sizes, int n_in,
                              void* d_out, int out_size, void* d_ws, size_t ws_size,
                              hipStream_t stream) {
    const float* x      = (const float*)d_in[0];
    const float* w_qkv  = (const float*)d_in[1];
    const float* w_proj = (const float*)d_in[2];
    const float* q_gain = (const float*)d_in[3];
    float* out = (float*)d_out;
    char* ws = (char*)d_ws;

    u16*   wqkv_b  = (u16*)(ws);                    // 3,145,728
    u16*   wproj_b = (u16*)(ws + 3145728);          // 2,097,152
    u16*   xb      = (u16*)(ws + 5242880);          // 8,388,608 (aliased: yb)
    float* qkv     = (float*)(ws + 13631488);       // 25,165,824 (aliased: y)
    u16*   Qb      = (u16*)(ws + 38797312);         // 8,388,608
    u16*   Kb      = (u16*)(ws + 47185920);         // 2,097,152
    u16*   Vt      = (u16*)(ws + 49283072);         // 2,097,152
    float* y  = qkv;
    u16*   yb = xb;

    quantize_ternary<<<6144, 256, 0, stream>>>(w_qkv, wqkv_b, 24576);
    quantize_ternary<<<4096, 256, 0, stream>>>(w_proj, wproj_b, 16384);
    cast_bf16<<<2048, 256, 0, stream>>>(x, xb);
    gemm_bt<<<dim3(12, 32), 256, 0, stream>>>(xb, wqkv_b, qkv, 4096, 1536, 1024);
    fuse_qkv<<<256, 256, 0, stream>>>(qkv, q_gain, Qb, Kb, Vt);
    attn<<<dim3(32, 32), 256, 0, stream>>>(Qb, Kb, Vt, y);
    rmsnorm_rows<<<4096, 256, 0, stream>>>(y, yb);
    gemm_bt<<<dim3(8, 32), 256, 0, stream>>>(yb, wproj_b, out, 4096, 1024, 1024);
}